// Round 4
// baseline (4344.962 us; speedup 1.0000x reference)
//
#include <hip/hip_runtime.h>
#include <hip/hip_bf16.h>
#include <math.h>

// Problem dims (fixed)
#define BATCHN   4
#define CHN      8
#define SEQ      1024
#define DMODEL   512
#define DSTATE   16
#define DCONV    4
#define DINNER   1024
#define DTRANK   32
#define NROWS    32768          // BATCH*CH*SEQ
#define XD       64             // DT_RANK + 2*D_STATE
#define NBC      32             // BATCH*CH (independent sequences)

// ---------------- GEMM: C[M,N] = A[M,K] * B[N,K]^T, fp32, tiled ----------------
#define TBM 64
#define TBN 64
#define TBK 16

enum { EPI_NONE = 0, EPI_GATE = 1 };   // EPI_GATE: C = C_old * silu(acc)

__device__ __forceinline__ float siluf(float v) {
    return v / (1.0f + expf(-v));
}
__device__ __forceinline__ float softplusf(float v) {
    return (v > 20.0f) ? v : log1pf(expf(v));
}

template <int EPI>
__global__ __launch_bounds__(256)
void gemm_atb(const float* __restrict__ A, int lda,
              const float* __restrict__ B, int ldb,
              float* __restrict__ C, int ldc,
              int K) {
    __shared__ float As[TBM][TBK + 1];
    __shared__ float Bs[TBN][TBK + 1];

    const int tid = threadIdx.x;
    const int tx = tid & 15;          // 0..15 -> N dir
    const int ty = tid >> 4;          // 0..15 -> M dir
    const int m0 = blockIdx.y * TBM;
    const int n0 = blockIdx.x * TBN;

    const int lr = tid >> 2;          // 0..63: tile row for loads
    const int lc = (tid & 3) * 4;     // 0,4,8,12: k offset for loads

    float acc[4][4];
#pragma unroll
    for (int i = 0; i < 4; ++i)
#pragma unroll
        for (int j = 0; j < 4; ++j) acc[i][j] = 0.0f;

    for (int k0 = 0; k0 < K; k0 += TBK) {
        const float4 av = *(const float4*)(A + (size_t)(m0 + lr) * lda + k0 + lc);
        const float4 bv = *(const float4*)(B + (size_t)(n0 + lr) * ldb + k0 + lc);
        As[lr][lc + 0] = av.x; As[lr][lc + 1] = av.y;
        As[lr][lc + 2] = av.z; As[lr][lc + 3] = av.w;
        Bs[lr][lc + 0] = bv.x; Bs[lr][lc + 1] = bv.y;
        Bs[lr][lc + 2] = bv.z; Bs[lr][lc + 3] = bv.w;
        __syncthreads();

#pragma unroll
        for (int kk = 0; kk < TBK; ++kk) {
            float a[4], b[4];
#pragma unroll
            for (int i = 0; i < 4; ++i) a[i] = As[ty * 4 + i][kk];
#pragma unroll
            for (int j = 0; j < 4; ++j) b[j] = Bs[tx * 4 + j][kk];
#pragma unroll
            for (int i = 0; i < 4; ++i)
#pragma unroll
                for (int j = 0; j < 4; ++j) acc[i][j] += a[i] * b[j];
        }
        __syncthreads();
    }

#pragma unroll
    for (int i = 0; i < 4; ++i) {
        const int r = m0 + ty * 4 + i;
#pragma unroll
        for (int j = 0; j < 4; ++j) {
            const int c = n0 + tx * 4 + j;
            const size_t off = (size_t)r * ldc + c;
            if (EPI == EPI_NONE) {
                C[off] = acc[i][j];
            } else { // EPI_GATE: acc is z; gate existing C (= y) in place
                C[off] = C[off] * siluf(acc[i][j]);
            }
        }
    }
}

// ---------------- depthwise causal conv (width 4) + bias + SiLU, IN PLACE ------
__global__ __launch_bounds__(256)
void conv_inplace_silu(float* __restrict__ xs,
                       const float* __restrict__ conv_w,
                       const float* __restrict__ conv_b) {
    const int gid = blockIdx.x * 256 + threadIdx.x;   // 0..NBC*DINNER-1
    const int d = gid & (DINNER - 1);
    const int b = gid >> 10;
    const float w0 = conv_w[d * DCONV + 0];
    const float w1 = conv_w[d * DCONV + 1];
    const float w2 = conv_w[d * DCONV + 2];
    const float w3 = conv_w[d * DCONV + 3];
    const float cb = conv_b[d];
    float x0 = 0.0f, x1 = 0.0f, x2 = 0.0f;
    size_t p = (size_t)b * SEQ * DINNER + d;
    for (int t = 0; t < SEQ; ++t, p += DINNER) {
        const float xv = xs[p];
        const float acc = cb + w0 * x0 + w1 * x1 + w2 * x2 + w3 * xv;
        xs[p] = siluf(acc);
        x0 = x1; x1 = x2; x2 = xv;
    }
}

// ---------------- selective scan v2: state-parallel (16 lanes per channel) -----
// Block = 256 threads = 16 channels (j) x 16 states (s). Grid = 32*64 = 2048.
// dt-projection: 2 terms/lane + 16-lane xor-butterfly; y: butterfly over h*C.
// xs / x_dbl staged per-SCHUNK in LDS; y staged in LDS, stored coalesced,
// written IN PLACE over xs (ungated; z-gating happens in the later gate GEMM).
#define SCHUNK 32
__global__ __launch_bounds__(256)
void scan_kernel(float* __restrict__ xs,              // in: conv'd x; out: y+x*D
                 const float* __restrict__ x_dbl,
                 const float* __restrict__ W_dt,
                 const float* __restrict__ b_dt,
                 const float* __restrict__ A_log,
                 const float* __restrict__ Dp) {
    const int tid = threadIdx.x;
    const int s = tid & 15;           // state
    const int j = tid >> 4;           // channel within block (0..15)
    const int b = blockIdx.x >> 6;    // sequence (0..31)
    const int d0 = (blockIdx.x & 63) << 4;
    const int d = d0 + j;

    const float wdt0 = W_dt[d * DTRANK + 2 * s];
    const float wdt1 = W_dt[d * DTRANK + 2 * s + 1];
    const float bdt = b_dt[d];
    const float Dv = Dp[d];
    const float a_s = -expf(A_log[d * DSTATE + s]);
    float h = 0.0f;

    __shared__ float bc[SCHUNK][XD];     // x_dbl rows (dt_in | B | C)
    __shared__ float xsh[SCHUNK][16];    // raw (conv'd) x chunk
    __shared__ float ysh[SCHUNK][16];    // y output staging

    const size_t brow = (size_t)b * SEQ;

    for (int t0 = 0; t0 < SEQ; t0 += SCHUNK) {
        __syncthreads();   // previous chunk's ysh fully consumed
        // stage x_dbl chunk: SCHUNK*XD floats = 512 float4
        for (int e = tid; e < SCHUNK * XD / 4; e += 256) {
            const int tt = e >> 4;
            const int c4 = (e & 15) * 4;
            const float4 v = *(const float4*)(x_dbl + (brow + t0 + tt) * XD + c4);
            bc[tt][c4 + 0] = v.x; bc[tt][c4 + 1] = v.y;
            bc[tt][c4 + 2] = v.z; bc[tt][c4 + 3] = v.w;
        }
        // stage xs chunk: SCHUNK*16 floats = 128 float4
        if (tid < SCHUNK * 4) {
            const int tt = tid >> 2;
            const int q = tid & 3;
            const float4 v = *(const float4*)(xs + (brow + t0 + tt) * DINNER + d0 + q * 4);
            xsh[tt][q * 4 + 0] = v.x; xsh[tt][q * 4 + 1] = v.y;
            xsh[tt][q * 4 + 2] = v.z; xsh[tt][q * 4 + 3] = v.w;
        }
        __syncthreads();

        for (int tt = 0; tt < SCHUNK; ++tt) {
            // dt = softplus(dt_in . W_dt[d,:] + b_dt[d]) via 16-lane butterfly
            float red = fmaf(bc[tt][2 * s], wdt0, bc[tt][2 * s + 1] * wdt1);
            red += __shfl_xor(red, 1, 16);
            red += __shfl_xor(red, 2, 16);
            red += __shfl_xor(red, 4, 16);
            red += __shfl_xor(red, 8, 16);
            const float dtv = softplusf(red + bdt);

            const float xv = xsh[tt][j];
            const float pre = dtv * xv;
            const float dA = expf(dtv * a_s);
            h = fmaf(dA, h, pre * bc[tt][DTRANK + s]);

            float yp = h * bc[tt][DTRANK + DSTATE + s];
            yp += __shfl_xor(yp, 1, 16);
            yp += __shfl_xor(yp, 2, 16);
            yp += __shfl_xor(yp, 4, 16);
            yp += __shfl_xor(yp, 8, 16);
            if (s == 0) ysh[tt][j] = fmaf(xv, Dv, yp);
        }
        __syncthreads();
        // store y chunk (ungated), in place over xs
        if (tid < SCHUNK * 4) {
            const int tt = tid >> 2;
            const int q = tid & 3;
            float4 v;
            v.x = ysh[tt][q * 4 + 0]; v.y = ysh[tt][q * 4 + 1];
            v.z = ysh[tt][q * 4 + 2]; v.w = ysh[tt][q * 4 + 3];
            *(float4*)(xs + (brow + t0 + tt) * DINNER + d0 + q * 4) = v;
        }
    }
}

// ---------------- launch ----------------
// Workspace budget: exactly NROWS*DINNER floats = 128 MiB.
// x_dbl (NROWS*64 floats = 8 MiB) is stashed in d_out and consumed by the
// scan BEFORE the final GEMM overwrites d_out (stream-ordered).
extern "C" void kernel_launch(void* const* d_in, const int* in_sizes, int n_in,
                              void* d_out, int out_size, void* d_ws, size_t ws_size,
                              hipStream_t stream) {
    const float* x       = (const float*)d_in[0];
    const float* W_in    = (const float*)d_in[1];
    const float* conv_w  = (const float*)d_in[2];
    const float* conv_b  = (const float*)d_in[3];
    const float* W_xproj = (const float*)d_in[4];
    const float* W_dt    = (const float*)d_in[5];
    const float* b_dt    = (const float*)d_in[6];
    const float* A_log   = (const float*)d_in[7];
    const float* Dp      = (const float*)d_in[8];
    const float* W_out   = (const float*)d_in[9];
    float* out = (float*)d_out;

    float* xs    = (float*)d_ws;     // BIG floats: xs -> conv'd -> y (in place)
    float* x_dbl = out;              // borrow d_out as scratch for x_dbl

    dim3 blk(256);

    // 1. xs = u @ W_in[0:1024]^T   (M=32768, N=1024, K=512)
    gemm_atb<EPI_NONE><<<dim3(DINNER / TBN, NROWS / TBM), blk, 0, stream>>>(
        x, DMODEL, W_in, DMODEL, xs, DINNER, DMODEL);

    // 2. depthwise conv + bias + SiLU, in place over xs
    conv_inplace_silu<<<NBC * DINNER / 256, blk, 0, stream>>>(xs, conv_w, conv_b);

    // 3. x_dbl = xs @ W_xproj^T    (M=32768, N=64, K=1024) -> stashed in d_out
    gemm_atb<EPI_NONE><<<dim3(XD / TBN, NROWS / TBM), blk, 0, stream>>>(
        xs, DINNER, W_xproj, DINNER, x_dbl, XD, DINNER);

    // 4. fused dt-proj + selective scan + D-skip; y (ungated) in place over xs
    scan_kernel<<<NBC * (DINNER / 16), blk, 0, stream>>>(xs, x_dbl, W_dt, b_dt, A_log, Dp);

    // 5. z-gate: z = u @ W_in[1024:2048]^T, xs *= silu(z)  (in-place epilogue)
    gemm_atb<EPI_GATE><<<dim3(DINNER / TBN, NROWS / TBM), blk, 0, stream>>>(
        x, DMODEL, W_in + (size_t)DINNER * DMODEL, DMODEL, xs, DINNER, DMODEL);

    // 6. out = y @ W_out^T         (M=32768, N=512, K=1024)
    gemm_atb<EPI_NONE><<<dim3(DMODEL / TBN, NROWS / TBM), blk, 0, stream>>>(
        xs, DINNER, W_out, DINNER, out, DMODEL, DINNER);
}

// Round 6
// 3110.010 us; speedup vs baseline: 1.3971x; 1.3971x over previous
//
#include <hip/hip_runtime.h>
#include <hip/hip_bf16.h>
#include <math.h>

// Problem dims (fixed)
#define BATCHN   4
#define CHN      8
#define SEQ      1024
#define DMODEL   512
#define DSTATE   16
#define DCONV    4
#define DINNER   1024
#define DTRANK   32
#define NROWS    32768          // BATCH*CH*SEQ
#define XD       64             // DT_RANK + 2*D_STATE
#define NBC      32             // BATCH*CH (independent sequences)

// Scan chunking
#define GCH   8                 // chunks per sequence
#define CLEN  (SEQ / GCH)       // 128 timesteps per chunk
#define SUB   32                // x_dbl LDS staging sub-chunk

// ---------------- GEMM: C[M,N] = A[M,K] * B[N,K]^T, fp32, tiled ----------------
#define TBM 64
#define TBN 64
#define TBK 16

enum { EPI_NONE = 0, EPI_GATE = 1 };   // EPI_GATE: C = C_old * silu(acc)

__device__ __forceinline__ float siluf(float v) {
    return v / (1.0f + expf(-v));
}
__device__ __forceinline__ float softplusf(float v) {
    return (v > 20.0f) ? v : log1pf(expf(v));
}

template <int EPI>
__global__ __launch_bounds__(256)
void gemm_atb(const float* __restrict__ A, int lda,
              const float* __restrict__ B, int ldb,
              float* __restrict__ C, int ldc,
              int K) {
    __shared__ float As[TBM][TBK + 1];
    __shared__ float Bs[TBN][TBK + 1];

    const int tid = threadIdx.x;
    const int tx = tid & 15;          // 0..15 -> N dir
    const int ty = tid >> 4;          // 0..15 -> M dir
    const int m0 = blockIdx.y * TBM;
    const int n0 = blockIdx.x * TBN;

    const int lr = tid >> 2;          // 0..63: tile row for loads
    const int lc = (tid & 3) * 4;     // 0,4,8,12: k offset for loads

    float acc[4][4];
#pragma unroll
    for (int i = 0; i < 4; ++i)
#pragma unroll
        for (int j = 0; j < 4; ++j) acc[i][j] = 0.0f;

    for (int k0 = 0; k0 < K; k0 += TBK) {
        const float4 av = *(const float4*)(A + (size_t)(m0 + lr) * lda + k0 + lc);
        const float4 bv = *(const float4*)(B + (size_t)(n0 + lr) * ldb + k0 + lc);
        As[lr][lc + 0] = av.x; As[lr][lc + 1] = av.y;
        As[lr][lc + 2] = av.z; As[lr][lc + 3] = av.w;
        Bs[lr][lc + 0] = bv.x; Bs[lr][lc + 1] = bv.y;
        Bs[lr][lc + 2] = bv.z; Bs[lr][lc + 3] = bv.w;
        __syncthreads();

#pragma unroll
        for (int kk = 0; kk < TBK; ++kk) {
            float a[4], b[4];
#pragma unroll
            for (int i = 0; i < 4; ++i) a[i] = As[ty * 4 + i][kk];
#pragma unroll
            for (int j = 0; j < 4; ++j) b[j] = Bs[tx * 4 + j][kk];
#pragma unroll
            for (int i = 0; i < 4; ++i)
#pragma unroll
                for (int j = 0; j < 4; ++j) acc[i][j] += a[i] * b[j];
        }
        __syncthreads();
    }

#pragma unroll
    for (int i = 0; i < 4; ++i) {
        const int r = m0 + ty * 4 + i;
#pragma unroll
        for (int j = 0; j < 4; ++j) {
            const int c = n0 + tx * 4 + j;
            const size_t off = (size_t)r * ldc + c;
            if (EPI == EPI_NONE) {
                C[off] = acc[i][j];
            } else { // EPI_GATE: acc is z; gate existing C (= y) in place
                C[off] = C[off] * siluf(acc[i][j]);
            }
        }
    }
}

// ---------------- depthwise causal conv (width 4) + bias + SiLU, IN PLACE ------
__global__ __launch_bounds__(256)
void conv_inplace_silu(float* __restrict__ xs,
                       const float* __restrict__ conv_w,
                       const float* __restrict__ conv_b) {
    const int gid = blockIdx.x * 256 + threadIdx.x;   // 0..NBC*DINNER-1
    const int d = gid & (DINNER - 1);
    const int b = gid >> 10;
    const float w0 = conv_w[d * DCONV + 0];
    const float w1 = conv_w[d * DCONV + 1];
    const float w2 = conv_w[d * DCONV + 2];
    const float w3 = conv_w[d * DCONV + 3];
    const float cb = conv_b[d];
    float x0 = 0.0f, x1 = 0.0f, x2 = 0.0f;
    size_t p = (size_t)b * SEQ * DINNER + d;
    for (int t = 0; t < SEQ; ++t, p += DINNER) {
        const float xv = xs[p];
        const float acc = cb + w0 * x0 + w1 * x1 + w2 * x2 + w3 * xv;
        xs[p] = siluf(acc);
        x0 = x1; x1 = x2; x2 = xv;
    }
}

// ---------------- chunked selective scan (2 passes, write-once scratch) --------
// h_t = dA_t h_{t-1} + w_t composes associatively -> split t into GCH chunks.
// PASS 0: per (b,d,chunk) compute P_s = prod(dA) and S_s = h_local(end),
//         store to ps (write-once).
// PASS 1: per (b,d,chunk) compose h_in from chunks 0..c-1 directly from ps
//         (no intermediate RMW kernel), re-walk chunk, write y+x*D over xs.
// ps layout: ps[((c*NBC + b)*32 + slot)*DINNER + d], slot 0..15 = P, 16..31 = S.
// Thread = one (b, d, chunk); lanes are consecutive d -> coalesced access.

__device__ __forceinline__ size_t ps_idx(int c, int b, int slot, int d) {
    return ((size_t)(c * NBC + b) * 32 + slot) * DINNER + d;
}

template <int PASS>
__global__ __launch_bounds__(256)
void scan_chunk_kernel(float* __restrict__ xs,        // in: conv'd x; out(P1): y+x*D
                       const float* __restrict__ x_dbl,
                       const float* __restrict__ W_dt,
                       const float* __restrict__ b_dt,
                       const float* __restrict__ A_log,
                       const float* __restrict__ Dp,
                       float* __restrict__ ps) {
    const int tid = threadIdx.x;
    const int c  = blockIdx.x & (GCH - 1);
    const int dg = (blockIdx.x >> 3) & 3;
    const int b  = blockIdx.x >> 5;
    const int d  = (dg << 8) + tid;

    float wdt[DTRANK];
#pragma unroll
    for (int k = 0; k < DTRANK; ++k) wdt[k] = W_dt[d * DTRANK + k];
    const float bdt = b_dt[d];
    const float Dv = Dp[d];

    float a[DSTATE], h[DSTATE], P[DSTATE];
#pragma unroll
    for (int s = 0; s < DSTATE; ++s) a[s] = -expf(A_log[d * DSTATE + s]);

    if (PASS == 0) {
#pragma unroll
        for (int s = 0; s < DSTATE; ++s) { h[s] = 0.0f; P[s] = 1.0f; }
    } else {
        // Fused chunk prefix: h_in = compose(chunks 0..c-1), read-only ps.
#pragma unroll
        for (int s = 0; s < DSTATE; ++s) h[s] = 0.0f;
        for (int j = 0; j < c; ++j) {       // wave-uniform trip count
#pragma unroll
            for (int s = 0; s < DSTATE; ++s) {
                const float Pj = ps[ps_idx(j, b, s, d)];
                const float Sj = ps[ps_idx(j, b, 16 + s, d)];
                h[s] = fmaf(Pj, h[s], Sj);
            }
        }
    }

    __shared__ float bc[SUB][XD];
    const size_t brow = (size_t)b * SEQ + (size_t)c * CLEN;

    for (int t0 = 0; t0 < CLEN; t0 += SUB) {
        __syncthreads();
        for (int e = tid; e < SUB * XD / 4; e += 256) {
            const int tt = e >> 4;
            const int c4 = (e & 15) * 4;
            const float4 v = *(const float4*)(x_dbl + (brow + t0 + tt) * XD + c4);
            bc[tt][c4 + 0] = v.x; bc[tt][c4 + 1] = v.y;
            bc[tt][c4 + 2] = v.z; bc[tt][c4 + 3] = v.w;
        }
        __syncthreads();

        for (int tt = 0; tt < SUB; ++tt) {
            float dtacc = bdt;
#pragma unroll
            for (int k = 0; k < DTRANK; ++k) dtacc = fmaf(bc[tt][k], wdt[k], dtacc);
            const float dtv = softplusf(dtacc);

            const size_t row = brow + t0 + tt;
            const float xv = xs[row * DINNER + d];
            const float pre = dtv * xv;
            float yv = 0.0f;
#pragma unroll
            for (int s = 0; s < DSTATE; ++s) {
                const float dA = expf(dtv * a[s]);
                h[s] = fmaf(dA, h[s], pre * bc[tt][DTRANK + s]);
                if (PASS == 0) P[s] *= dA;
                else yv = fmaf(h[s], bc[tt][DTRANK + DSTATE + s], yv);
            }
            if (PASS == 1) xs[row * DINNER + d] = fmaf(xv, Dv, yv);
        }
    }

    if (PASS == 0) {
#pragma unroll
        for (int s = 0; s < DSTATE; ++s) {
            ps[ps_idx(c, b, s, d)]      = P[s];
            ps[ps_idx(c, b, 16 + s, d)] = h[s];
        }
    }
}

// ---------------- launch ----------------
// Workspace: NROWS*DINNER floats = 128 MiB (xs -> conv'd -> y, in place).
// d_out doubles as scratch before the final GEMM: x_dbl (8 MiB) + PS (32 MiB).
// d_out is zeroed at launch start so every call (first validation, graph
// replay, fresh tripwire launch) starts from the identical scratch state.
extern "C" void kernel_launch(void* const* d_in, const int* in_sizes, int n_in,
                              void* d_out, int out_size, void* d_ws, size_t ws_size,
                              hipStream_t stream) {
    const float* x       = (const float*)d_in[0];
    const float* W_in    = (const float*)d_in[1];
    const float* conv_w  = (const float*)d_in[2];
    const float* conv_b  = (const float*)d_in[3];
    const float* W_xproj = (const float*)d_in[4];
    const float* W_dt    = (const float*)d_in[5];
    const float* b_dt    = (const float*)d_in[6];
    const float* A_log   = (const float*)d_in[7];
    const float* Dp      = (const float*)d_in[8];
    const float* W_out   = (const float*)d_in[9];
    float* out = (float*)d_out;

    float* xs    = (float*)d_ws;             // BIG floats, in-place pipeline
    float* x_dbl = out;                      // d_out[0 .. 2M)
    float* ps    = out + (size_t)NROWS * XD; // d_out[2M .. 10.5M) of 16.7M

    dim3 blk(256);

    // 0. normalize scratch initial state (capture-legal memset node)
    hipMemsetAsync(d_out, 0, (size_t)out_size * sizeof(float), stream);

    // 1. xs = u @ W_in[0:1024]^T   (M=32768, N=1024, K=512)
    gemm_atb<EPI_NONE><<<dim3(DINNER / TBN, NROWS / TBM), blk, 0, stream>>>(
        x, DMODEL, W_in, DMODEL, xs, DINNER, DMODEL);

    // 2. depthwise conv + bias + SiLU, in place over xs
    conv_inplace_silu<<<NBC * DINNER / 256, blk, 0, stream>>>(xs, conv_w, conv_b);

    // 3. x_dbl = xs @ W_xproj^T    (M=32768, N=64, K=1024) -> stashed in d_out
    gemm_atb<EPI_NONE><<<dim3(XD / TBN, NROWS / TBM), blk, 0, stream>>>(
        xs, DINNER, W_xproj, DINNER, x_dbl, XD, DINNER);

    // 4a. chunk-local (P, S) -> ps (write-once)
    scan_chunk_kernel<0><<<NBC * 4 * GCH, blk, 0, stream>>>(
        xs, x_dbl, W_dt, b_dt, A_log, Dp, ps);
    // 4b. fused prefix + re-walk chunks, write ungated y + x*D over xs
    scan_chunk_kernel<1><<<NBC * 4 * GCH, blk, 0, stream>>>(
        xs, x_dbl, W_dt, b_dt, A_log, Dp, ps);

    // 5. z-gate: z = u @ W_in[1024:2048]^T, xs *= silu(z)  (in-place epilogue)
    gemm_atb<EPI_GATE><<<dim3(DINNER / TBN, NROWS / TBM), blk, 0, stream>>>(
        x, DMODEL, W_in + (size_t)DINNER * DMODEL, DMODEL, xs, DINNER, DMODEL);

    // 6. out = y @ W_out^T         (M=32768, N=512, K=1024)
    gemm_atb<EPI_NONE><<<dim3(DMODEL / TBN, NROWS / TBM), blk, 0, stream>>>(
        xs, DINNER, W_out, DINNER, out, DMODEL, DINNER);
}

// Round 7
// 1568.455 us; speedup vs baseline: 2.7702x; 1.9828x over previous
//
#include <hip/hip_runtime.h>
#include <hip/hip_bf16.h>
#include <math.h>

// Problem dims (fixed)
#define BATCHN   4
#define CHN      8
#define SEQ      1024
#define DMODEL   512
#define DSTATE   16
#define DCONV    4
#define DINNER   1024
#define DTRANK   32
#define NROWS    32768          // BATCH*CH*SEQ
#define XD       64             // DT_RANK + 2*D_STATE
#define NBC      32             // BATCH*CH (independent sequences)

// Scan chunking
#define GCH   8                 // chunks per sequence
#define CLEN  (SEQ / GCH)       // 128 timesteps per chunk
#define SUB   32                // x_dbl LDS staging sub-chunk

enum { EPI_NONE = 0, EPI_GATE = 1 };   // EPI_GATE: C = C_old * silu(acc)

__device__ __forceinline__ float siluf(float v) {
    return v / (1.0f + expf(-v));
}
__device__ __forceinline__ float softplusf(float v) {
    return (v > 20.0f) ? v : log1pf(expf(v));
}

// ---------------- bf16-split MFMA GEMM: C[M,N] = A[M,K] * B[N,K]^T --------------
// fp32 inputs are split on the fly into hi+lo bf16 (x = hi + lo, each bf16);
// acc += hi*hi + lo*hi + hi*lo in fp32 AGPRs -> ~2^-17 relative error.
// Block tile 128x128, BK=32, 256 threads = 4 waves, each wave 64x64 via a
// 4x4 grid of 16x16x32 MFMA fragments (48 MFMAs per wave per K-step).
// LDS rows padded to 40 shorts (80 B = 20 banks) to break power-of-2 aliasing.

typedef short short8 __attribute__((ext_vector_type(8)));
typedef float floatx4 __attribute__((ext_vector_type(4)));

__device__ __forceinline__ unsigned short f2bf_rne(float f) {
    unsigned int u = __float_as_uint(f);
    u += 0x7fffu + ((u >> 16) & 1u);
    return (unsigned short)(u >> 16);
}
__device__ __forceinline__ float bf2f(unsigned short h) {
    return __uint_as_float(((unsigned int)h) << 16);
}

template <int EPI>
__global__ __launch_bounds__(256, 2)
void gemm_mfma_split(const float* __restrict__ A, int lda,
                     const float* __restrict__ B, int ldb,
                     float* __restrict__ C, int ldc,
                     int K) {
    __shared__ __align__(16) unsigned short Ah[128][40];
    __shared__ __align__(16) unsigned short Al[128][40];
    __shared__ __align__(16) unsigned short Bh[128][40];
    __shared__ __align__(16) unsigned short Bl[128][40];

    const int tid  = threadIdx.x;
    const int lane = tid & 63;
    const int wv   = tid >> 6;
    const int quad = lane >> 4;
    const int m16  = lane & 15;
    const int wm   = (wv & 1) * 64;       // wave's m-offset in block tile
    const int wn   = (wv >> 1) * 64;      // wave's n-offset
    const int m0   = blockIdx.y * 128;
    const int n0   = blockIdx.x * 128;

    const int srow = tid >> 1;            // staging row 0..127
    const int skb  = (tid & 1) * 16;      // staging k-offset 0 / 16

    floatx4 acc[4][4];
#pragma unroll
    for (int i = 0; i < 4; ++i)
#pragma unroll
        for (int j = 0; j < 4; ++j) acc[i][j] = (floatx4){0.f, 0.f, 0.f, 0.f};

    union U { short8 v; unsigned short u[8]; };

    for (int k0 = 0; k0 < K; k0 += 32) {
        // global loads first (overlap with the barrier)
        const float* ap = A + (size_t)(m0 + srow) * lda + k0 + skb;
        const float* bp = B + (size_t)(n0 + srow) * ldb + k0 + skb;
        const float4 a0 = *(const float4*)(ap + 0);
        const float4 a1 = *(const float4*)(ap + 4);
        const float4 a2 = *(const float4*)(ap + 8);
        const float4 a3 = *(const float4*)(ap + 12);
        const float4 b0 = *(const float4*)(bp + 0);
        const float4 b1 = *(const float4*)(bp + 4);
        const float4 b2 = *(const float4*)(bp + 8);
        const float4 b3 = *(const float4*)(bp + 12);
        const float af[16] = {a0.x, a0.y, a0.z, a0.w, a1.x, a1.y, a1.z, a1.w,
                              a2.x, a2.y, a2.z, a2.w, a3.x, a3.y, a3.z, a3.w};
        const float bf[16] = {b0.x, b0.y, b0.z, b0.w, b1.x, b1.y, b1.z, b1.w,
                              b2.x, b2.y, b2.z, b2.w, b3.x, b3.y, b3.z, b3.w};

        U ah0, ah1, al0, al1, bh0, bh1, bl0, bl1;
#pragma unroll
        for (int e = 0; e < 8; ++e) {
            const unsigned short ha = f2bf_rne(af[e]);
            ah0.u[e] = ha; al0.u[e] = f2bf_rne(af[e] - bf2f(ha));
            const unsigned short hb = f2bf_rne(bf[e]);
            bh0.u[e] = hb; bl0.u[e] = f2bf_rne(bf[e] - bf2f(hb));
        }
#pragma unroll
        for (int e = 0; e < 8; ++e) {
            const unsigned short ha = f2bf_rne(af[8 + e]);
            ah1.u[e] = ha; al1.u[e] = f2bf_rne(af[8 + e] - bf2f(ha));
            const unsigned short hb = f2bf_rne(bf[8 + e]);
            bh1.u[e] = hb; bl1.u[e] = f2bf_rne(bf[8 + e] - bf2f(hb));
        }

        __syncthreads();   // all waves done reading previous tile
        *(short8*)&Ah[srow][skb]     = ah0.v;
        *(short8*)&Ah[srow][skb + 8] = ah1.v;
        *(short8*)&Al[srow][skb]     = al0.v;
        *(short8*)&Al[srow][skb + 8] = al1.v;
        *(short8*)&Bh[srow][skb]     = bh0.v;
        *(short8*)&Bh[srow][skb + 8] = bh1.v;
        *(short8*)&Bl[srow][skb]     = bl0.v;
        *(short8*)&Bl[srow][skb + 8] = bl1.v;
        __syncthreads();

        short8 a_h[4], a_l[4], b_h[4], b_l[4];
#pragma unroll
        for (int i = 0; i < 4; ++i) {
            a_h[i] = *(const short8*)&Ah[wm + i * 16 + m16][quad * 8];
            a_l[i] = *(const short8*)&Al[wm + i * 16 + m16][quad * 8];
            b_h[i] = *(const short8*)&Bh[wn + i * 16 + m16][quad * 8];
            b_l[i] = *(const short8*)&Bl[wn + i * 16 + m16][quad * 8];
        }
#pragma unroll
        for (int i = 0; i < 4; ++i)
#pragma unroll
            for (int j = 0; j < 4; ++j) {
                acc[i][j] = __builtin_amdgcn_mfma_f32_16x16x32_bf16(
                    a_h[i], b_h[j], acc[i][j], 0, 0, 0);
                acc[i][j] = __builtin_amdgcn_mfma_f32_16x16x32_bf16(
                    a_l[i], b_h[j], acc[i][j], 0, 0, 0);
                acc[i][j] = __builtin_amdgcn_mfma_f32_16x16x32_bf16(
                    a_h[i], b_l[j], acc[i][j], 0, 0, 0);
            }
    }

    // Epilogue. C/D layout: col = lane&15, row = quad*4 + reg [m89/m91 verified]
#pragma unroll
    for (int i = 0; i < 4; ++i)
#pragma unroll
        for (int j = 0; j < 4; ++j) {
            const int col = n0 + wn + j * 16 + m16;
#pragma unroll
            for (int r = 0; r < 4; ++r) {
                const int row = m0 + wm + i * 16 + quad * 4 + r;
                const size_t off = (size_t)row * ldc + col;
                const float v = acc[i][j][r];
                if (EPI == EPI_NONE) C[off] = v;
                else                 C[off] = C[off] * siluf(v);
            }
        }
}

// ---------------- fp32 GEMM (kept for the small N=64 x-proj) -------------------
#define TBM 64
#define TBN 64
#define TBK 16

__global__ __launch_bounds__(256)
void gemm_atb(const float* __restrict__ A, int lda,
              const float* __restrict__ B, int ldb,
              float* __restrict__ C, int ldc,
              int K) {
    __shared__ float As[TBM][TBK + 1];
    __shared__ float Bs[TBN][TBK + 1];

    const int tid = threadIdx.x;
    const int tx = tid & 15;
    const int ty = tid >> 4;
    const int m0 = blockIdx.y * TBM;
    const int n0 = blockIdx.x * TBN;

    const int lr = tid >> 2;
    const int lc = (tid & 3) * 4;

    float acc[4][4];
#pragma unroll
    for (int i = 0; i < 4; ++i)
#pragma unroll
        for (int j = 0; j < 4; ++j) acc[i][j] = 0.0f;

    for (int k0 = 0; k0 < K; k0 += TBK) {
        const float4 av = *(const float4*)(A + (size_t)(m0 + lr) * lda + k0 + lc);
        const float4 bv = *(const float4*)(B + (size_t)(n0 + lr) * ldb + k0 + lc);
        As[lr][lc + 0] = av.x; As[lr][lc + 1] = av.y;
        As[lr][lc + 2] = av.z; As[lr][lc + 3] = av.w;
        Bs[lr][lc + 0] = bv.x; Bs[lr][lc + 1] = bv.y;
        Bs[lr][lc + 2] = bv.z; Bs[lr][lc + 3] = bv.w;
        __syncthreads();

#pragma unroll
        for (int kk = 0; kk < TBK; ++kk) {
            float a[4], b[4];
#pragma unroll
            for (int i = 0; i < 4; ++i) a[i] = As[ty * 4 + i][kk];
#pragma unroll
            for (int j = 0; j < 4; ++j) b[j] = Bs[tx * 4 + j][kk];
#pragma unroll
            for (int i = 0; i < 4; ++i)
#pragma unroll
                for (int j = 0; j < 4; ++j) acc[i][j] += a[i] * b[j];
        }
        __syncthreads();
    }

#pragma unroll
    for (int i = 0; i < 4; ++i) {
        const int r = m0 + ty * 4 + i;
#pragma unroll
        for (int j = 0; j < 4; ++j) {
            const int c = n0 + tx * 4 + j;
            C[(size_t)r * ldc + c] = acc[i][j];
        }
    }
}

// ---------------- depthwise causal conv (width 4) + bias + SiLU, IN PLACE ------
__global__ __launch_bounds__(256)
void conv_inplace_silu(float* __restrict__ xs,
                       const float* __restrict__ conv_w,
                       const float* __restrict__ conv_b) {
    const int gid = blockIdx.x * 256 + threadIdx.x;   // 0..NBC*DINNER-1
    const int d = gid & (DINNER - 1);
    const int b = gid >> 10;
    const float w0 = conv_w[d * DCONV + 0];
    const float w1 = conv_w[d * DCONV + 1];
    const float w2 = conv_w[d * DCONV + 2];
    const float w3 = conv_w[d * DCONV + 3];
    const float cb = conv_b[d];
    float x0 = 0.0f, x1 = 0.0f, x2 = 0.0f;
    size_t p = (size_t)b * SEQ * DINNER + d;
    for (int t = 0; t < SEQ; ++t, p += DINNER) {
        const float xv = xs[p];
        const float acc = cb + w0 * x0 + w1 * x1 + w2 * x2 + w3 * xv;
        xs[p] = siluf(acc);
        x0 = x1; x1 = x2; x2 = xv;
    }
}

// ---------------- chunked selective scan (2 passes, write-once scratch) --------
__device__ __forceinline__ size_t ps_idx(int c, int b, int slot, int d) {
    return ((size_t)(c * NBC + b) * 32 + slot) * DINNER + d;
}

template <int PASS>
__global__ __launch_bounds__(256)
void scan_chunk_kernel(float* __restrict__ xs,        // in: conv'd x; out(P1): y+x*D
                       const float* __restrict__ x_dbl,
                       const float* __restrict__ W_dt,
                       const float* __restrict__ b_dt,
                       const float* __restrict__ A_log,
                       const float* __restrict__ Dp,
                       float* __restrict__ ps) {
    const int tid = threadIdx.x;
    const int c  = blockIdx.x & (GCH - 1);
    const int dg = (blockIdx.x >> 3) & 3;
    const int b  = blockIdx.x >> 5;
    const int d  = (dg << 8) + tid;

    float wdt[DTRANK];
#pragma unroll
    for (int k = 0; k < DTRANK; ++k) wdt[k] = W_dt[d * DTRANK + k];
    const float bdt = b_dt[d];
    const float Dv = Dp[d];

    float a[DSTATE], h[DSTATE], P[DSTATE];
#pragma unroll
    for (int s = 0; s < DSTATE; ++s) a[s] = -expf(A_log[d * DSTATE + s]);

    if (PASS == 0) {
#pragma unroll
        for (int s = 0; s < DSTATE; ++s) { h[s] = 0.0f; P[s] = 1.0f; }
    } else {
        // Fused chunk prefix: h_in = compose(chunks 0..c-1), read-only ps.
#pragma unroll
        for (int s = 0; s < DSTATE; ++s) h[s] = 0.0f;
        for (int j = 0; j < c; ++j) {       // wave-uniform trip count
#pragma unroll
            for (int s = 0; s < DSTATE; ++s) {
                const float Pj = ps[ps_idx(j, b, s, d)];
                const float Sj = ps[ps_idx(j, b, 16 + s, d)];
                h[s] = fmaf(Pj, h[s], Sj);
            }
        }
    }

    __shared__ float bc[SUB][XD];
    const size_t brow = (size_t)b * SEQ + (size_t)c * CLEN;

    for (int t0 = 0; t0 < CLEN; t0 += SUB) {
        __syncthreads();
        for (int e = tid; e < SUB * XD / 4; e += 256) {
            const int tt = e >> 4;
            const int c4 = (e & 15) * 4;
            const float4 v = *(const float4*)(x_dbl + (brow + t0 + tt) * XD + c4);
            bc[tt][c4 + 0] = v.x; bc[tt][c4 + 1] = v.y;
            bc[tt][c4 + 2] = v.z; bc[tt][c4 + 3] = v.w;
        }
        __syncthreads();

        for (int tt = 0; tt < SUB; ++tt) {
            float dtacc = bdt;
#pragma unroll
            for (int k = 0; k < DTRANK; ++k) dtacc = fmaf(bc[tt][k], wdt[k], dtacc);
            const float dtv = softplusf(dtacc);

            const size_t row = brow + t0 + tt;
            const float xv = xs[row * DINNER + d];
            const float pre = dtv * xv;
            float yv = 0.0f;
#pragma unroll
            for (int s = 0; s < DSTATE; ++s) {
                const float dA = expf(dtv * a[s]);
                h[s] = fmaf(dA, h[s], pre * bc[tt][DTRANK + s]);
                if (PASS == 0) P[s] *= dA;
                else yv = fmaf(h[s], bc[tt][DTRANK + DSTATE + s], yv);
            }
            if (PASS == 1) xs[row * DINNER + d] = fmaf(xv, Dv, yv);
        }
    }

    if (PASS == 0) {
#pragma unroll
        for (int s = 0; s < DSTATE; ++s) {
            ps[ps_idx(c, b, s, d)]      = P[s];
            ps[ps_idx(c, b, 16 + s, d)] = h[s];
        }
    }
}

// ---------------- launch ----------------
// Workspace: NROWS*DINNER floats = 128 MiB (xs -> conv'd -> y, in place).
// d_out doubles as scratch before the final GEMM: x_dbl (8 MiB) + PS (32 MiB).
extern "C" void kernel_launch(void* const* d_in, const int* in_sizes, int n_in,
                              void* d_out, int out_size, void* d_ws, size_t ws_size,
                              hipStream_t stream) {
    const float* x       = (const float*)d_in[0];
    const float* W_in    = (const float*)d_in[1];
    const float* conv_w  = (const float*)d_in[2];
    const float* conv_b  = (const float*)d_in[3];
    const float* W_xproj = (const float*)d_in[4];
    const float* W_dt    = (const float*)d_in[5];
    const float* b_dt    = (const float*)d_in[6];
    const float* A_log   = (const float*)d_in[7];
    const float* Dp      = (const float*)d_in[8];
    const float* W_out   = (const float*)d_in[9];
    float* out = (float*)d_out;

    float* xs    = (float*)d_ws;             // BIG floats, in-place pipeline
    float* x_dbl = out;                      // d_out[0 .. 2M)
    float* ps    = out + (size_t)NROWS * XD; // d_out[2M .. 10.5M) of 16.7M

    dim3 blk(256);

    // 0. normalize scratch initial state (capture-legal memset node)
    hipMemsetAsync(d_out, 0, (size_t)out_size * sizeof(float), stream);

    // 1. xs = u @ W_in[0:1024]^T   (M=32768, N=1024, K=512)  [MFMA bf16-split]
    gemm_mfma_split<EPI_NONE><<<dim3(DINNER / 128, NROWS / 128), blk, 0, stream>>>(
        x, DMODEL, W_in, DMODEL, xs, DINNER, DMODEL);

    // 2. depthwise conv + bias + SiLU, in place over xs
    conv_inplace_silu<<<NBC * DINNER / 256, blk, 0, stream>>>(xs, conv_w, conv_b);

    // 3. x_dbl = xs @ W_xproj^T    (M=32768, N=64, K=1024) -> stashed in d_out
    gemm_atb<<<dim3(XD / TBN, NROWS / TBM), blk, 0, stream>>>(
        xs, DINNER, W_xproj, DINNER, x_dbl, XD, DINNER);

    // 4a. chunk-local (P, S) -> ps (write-once)
    scan_chunk_kernel<0><<<NBC * 4 * GCH, blk, 0, stream>>>(
        xs, x_dbl, W_dt, b_dt, A_log, Dp, ps);
    // 4b. fused prefix + re-walk chunks, write ungated y + x*D over xs
    scan_chunk_kernel<1><<<NBC * 4 * GCH, blk, 0, stream>>>(
        xs, x_dbl, W_dt, b_dt, A_log, Dp, ps);

    // 5. z-gate: z = u @ W_in[1024:2048]^T, xs *= silu(z)  [MFMA bf16-split]
    gemm_mfma_split<EPI_GATE><<<dim3(DINNER / 128, NROWS / 128), blk, 0, stream>>>(
        x, DMODEL, W_in + (size_t)DINNER * DMODEL, DMODEL, xs, DINNER, DMODEL);

    // 6. out = y @ W_out^T         (M=32768, N=512, K=1024)  [MFMA bf16-split]
    gemm_mfma_split<EPI_NONE><<<dim3(DMODEL / 128, NROWS / 128), blk, 0, stream>>>(
        xs, DINNER, W_out, DINNER, out, DMODEL, DINNER);
}